// Round 19
// baseline (30.359 us; speedup 1.0000x reference)
//
#include <hip/hip_runtime.h>

// NNLoss: min over 5x5 shifted neighborhoods of channel-summed L1 distance,
// then global mean. B=16, C=3, H=W=512, fp32.
// R19: R18 (conflict-free 4px x 2row compute, correct w0, no spill) with
// TH=8 tiles: LDS 38.6 KB -> 4 blocks/CU (2x more cross-block stage/compute
// overlap). Interior staging by wave-row: 12 rows/ch / 4 waves = 3 rows
// each (r = wid+4i, k = lane) -> zero div/mod, unconditional defs,
// perfectly coalesced. Edge f4 + PADV fixup by disjoint thread ranges.

#define PADV (-10000.0f)

constexpr int Bn = 16, Cn = 3, Hn = 512, Wn = 512;
constexpr long PLANE = (long)Hn * Wn;                  // 262144

constexpr int TW = 256, TH = 8;
constexpr int GW = 268;                                // 268 % 32 == 12
constexpr int GH = TH + 4;                             // 12 rows: h0-2..h0+9
constexpr int F4ROW = 66;                              // 264 floats: w0-4..w0+259
constexpr int F4T = Cn * GH * F4ROW;                   // 2376
constexpr int BLOCK = 256;
constexpr int NBANDS = Hn / TH;                        // 64
constexpr int NBLOCKS = Bn * 2 * NBANDS;               // 2048

__global__ __launch_bounds__(BLOCK, 2) void nnloss_main(
    const float* __restrict__ pred, const float* __restrict__ gt,
    float* __restrict__ partial) {
  // bijective XCD swizzle: each XCD owns 256 consecutive wg (band fastest)
  const int wg = ((blockIdx.x & 7) << 8) | (blockIdx.x >> 3);
  const int band = wg & (NBANDS - 1);
  const int tw = (wg >> 6) & 1;
  const int b = wg >> 7;
  const int w0 = tw * TW;
  const int h0 = band * TH;

  __shared__ __align__(16) float tile[Cn][GH][GW];     // 38,592 B

  const float* gb = gt + (long)b * Cn * PLANE;
  const float* pb = pred + (long)b * Cn * PLANE;

  const int tid = threadIdx.x;
  const int lane = tid & 63;
  const int wid = tid >> 6;                            // 4 waves
  const bool rowsafe = (band >= 1) && (band <= NBANDS - 2);
  const int ek = (tw == 0) ? 0 : 65;                   // fully-OOB edge f4

  // ---- pred: 4 px x 2 rows per thread (coalesced, issued early) ----
  const int tx = lane;                                 // 64 strips of 4 px
  const int row0 = 2 * wid;                            // 4 row-pairs
  float p[2][Cn][4];
  {
    const float* pp = pb + (long)(h0 + row0) * Wn + (w0 + 4 * tx);
#pragma unroll
    for (int r = 0; r < 2; ++r)
#pragma unroll
      for (int c = 0; c < Cn; ++c) {
        const float4 v = *(const float4*)(pp + (long)c * PLANE + (long)r * Wn);
        p[r][c][0] = v.x; p[r][c][1] = v.y; p[r][c][2] = v.z; p[r][c][3] = v.w;
      }
  }

  if (rowsafe) {
    // ---- interior staging: wave-row mapping, zero div/mod ----
    // wave wid stages rows r = wid, wid+4, wid+8 of each channel; lane = k.
    const int col0 = w0 - 4 + 4 * lane;
    const int gcc = min(max(col0, 0), Wn - 4);         // clamps only k=0@tw0
    float4 bv[Cn][3];
#pragma unroll
    for (int c = 0; c < Cn; ++c)
#pragma unroll
      for (int i = 0; i < 3; ++i) {
        const int r = wid + 4 * i;
        bv[c][i] = *(const float4*)(gb + (long)c * PLANE +
                                    (long)(h0 - 2 + r) * Wn + gcc);
      }
    // edge f4 (k=64,65): cols w0+252 / w0+256 (clamped at tw=1,k=65)
    float4 ev;
    int ec = 0, er = 0, ekk = 64;
    if (tid < 72) {
      ec = tid / 24;
      const int rem = tid - ec * 24;
      er = rem >> 1;
      ekk = 64 + (rem & 1);
      const int ce = min(w0 - 4 + 4 * ekk, Wn - 4);
      ev = *(const float4*)(gb + (long)ec * PLANE + (long)(h0 - 2 + er) * Wn + ce);
    }
    // writes (skip the OOB edge f4 -> no race with fixup)
#pragma unroll
    for (int c = 0; c < Cn; ++c)
#pragma unroll
      for (int i = 0; i < 3; ++i) {
        const int r = wid + 4 * i;
        if (!(tw == 0 && lane == 0))
          *(float4*)&tile[c][r][4 * lane] = bv[c][i];
      }
    if (tid < 72 && !(tw == 1 && ekk == 65))
      *(float4*)&tile[ec][er][4 * ekk] = ev;
    if (tid >= 72 && tid < 72 + Cn * GH) {             // PADV fixup
      const int t2 = tid - 72;
      const int c = t2 / GH;
      const int r = t2 - c * GH;
      *(float4*)&tile[c][r][4 * ek] = make_float4(PADV, PADV, PADV, PADV);
    }
  } else {
    // ---- boundary bands (0,63): generic gather + select path ----
    float4 sv[10];
#pragma unroll
    for (int m = 0; m < 10; ++m) {
      const int idx = tid + m * BLOCK;
      if (idx < F4T) {
        const int c = idx / (GH * F4ROW);
        const int rem = idx - c * (GH * F4ROW);
        const int r = rem / F4ROW;
        const int k = rem - r * F4ROW;
        const int ghc = min(max(h0 - 2 + r, 0), Hn - 1);
        const int gcc = min(max(w0 - 4 + 4 * k, 0), Wn - 4);
        sv[m] = *(const float4*)(gb + (long)c * PLANE + (long)ghc * Wn + gcc);
      }
    }
#pragma unroll
    for (int m = 0; m < 10; ++m) {
      const int idx = tid + m * BLOCK;
      if (idx < F4T) {
        const int c = idx / (GH * F4ROW);
        const int rem = idx - c * (GH * F4ROW);
        const int r = rem / F4ROW;
        const int k = rem - r * F4ROW;
        const int gh = h0 - 2 + r;
        const int gc0 = w0 - 4 + 4 * k;
        const bool rb = (gh < 0) || (gh >= Hn);
        float4 v = sv[m];
        v.x = (rb || gc0 + 0 < 0 || gc0 + 0 >= Wn) ? PADV : v.x;
        v.y = (rb || gc0 + 1 < 0 || gc0 + 1 >= Wn) ? PADV : v.y;
        v.z = (rb || gc0 + 2 < 0 || gc0 + 2 >= Wn) ? PADV : v.z;
        v.w = (rb || gc0 + 3 < 0 || gc0 + 3 >= Wn) ? PADV : v.w;
        *(float4*)&tile[c][r][4 * k] = v;
      }
    }
  }
  __syncthreads();

  // ---- compute: LDS rows row0..row0+5 read once, serve both output rows ----
  float mm[2][4];
#pragma unroll
  for (int r = 0; r < 2; ++r)
#pragma unroll
    for (int q = 0; q < 4; ++q) mm[r][q] = 3.0e38f;

#pragma unroll
  for (int rowIdx = 0; rowIdx < 6; ++rowIdx) {
    const int lr = row0 + rowIdx;
    float g[Cn][10];
#pragma unroll
    for (int c = 0; c < Cn; ++c) {
      // window cols L = 4tx+2 .. 4tx+9 ; g[k] = col 4tx+k
      const float* base = &tile[c][lr][4 * tx];
      const float4 A = *(const float4*)(base);
      const float4 Bq = *(const float4*)(base + 4);
      const float2 Cq = *(const float2*)(base + 8);
      g[c][0] = A.x;  g[c][1] = A.y;  g[c][2] = A.z;  g[c][3] = A.w;
      g[c][4] = Bq.x; g[c][5] = Bq.y; g[c][6] = Bq.z; g[c][7] = Bq.w;
      g[c][8] = Cq.x; g[c][9] = Cq.y;
    }
#pragma unroll
    for (int r = 0; r < 2; ++r) {
      const int di = rowIdx - r;
      if (di < 0 || di > 4) continue;                  // compile-time pruned
      float s[5][4];
#pragma unroll
      for (int dj = 0; dj < 5; ++dj)
#pragma unroll
        for (int q = 0; q < 4; ++q)
          s[dj][q] = fabsf(g[0][q + dj + 2] - p[r][0][q]);
#pragma unroll
      for (int c = 1; c < Cn; ++c)
#pragma unroll
        for (int dj = 0; dj < 5; ++dj)
#pragma unroll
          for (int q = 0; q < 4; ++q)
            s[dj][q] += fabsf(g[c][q + dj + 2] - p[r][c][q]);
#pragma unroll
      for (int q = 0; q < 4; ++q) {
        const float t1 = fminf(fminf(s[0][q], s[1][q]), s[2][q]);  // v_min3
        const float t2 = fminf(fminf(t1, s[3][q]), s[4][q]);       // v_min3
        mm[r][q] = fminf(mm[r][q], t2);
      }
    }
  }

  float v = ((mm[0][0] + mm[0][1]) + (mm[0][2] + mm[0][3])) +
            ((mm[1][0] + mm[1][1]) + (mm[1][2] + mm[1][3]));

  // ---- block reduction ----
#pragma unroll
  for (int off = 32; off > 0; off >>= 1) v += __shfl_down(v, off, 64);
  __shared__ float wsum[BLOCK / 64];
  if (lane == 0) wsum[wid] = v;
  __syncthreads();
  if (tid == 0)
    partial[blockIdx.x] = (wsum[0] + wsum[1]) + (wsum[2] + wsum[3]);
}

__global__ __launch_bounds__(256) void nnloss_reduce(
    const float* __restrict__ partial, float* __restrict__ out) {
  double acc = 0.0;
  for (int i = threadIdx.x; i < NBLOCKS; i += 256) acc += (double)partial[i];
#pragma unroll
  for (int off = 32; off > 0; off >>= 1) acc += __shfl_down(acc, off, 64);
  __shared__ double sd[4];
  const int lane = threadIdx.x & 63;
  const int wid = threadIdx.x >> 6;
  if (lane == 0) sd[wid] = acc;
  __syncthreads();
  if (threadIdx.x == 0) {
    const double tot = (sd[0] + sd[1]) + (sd[2] + sd[3]);
    out[0] = (float)(tot / ((double)Bn * Hn * Wn));
  }
}

extern "C" void kernel_launch(void* const* d_in, const int* in_sizes, int n_in,
                              void* d_out, int out_size, void* d_ws, size_t ws_size,
                              hipStream_t stream) {
  const float* pred = (const float*)d_in[0];
  const float* gt = (const float*)d_in[1];
  // d_in[2], d_in[3] are nh=5, nw=5 (hard-coded)
  float* out = (float*)d_out;
  float* partial = (float*)d_ws;  // 2048 floats = 8 KB

  nnloss_main<<<NBLOCKS, BLOCK, 0, stream>>>(pred, gt, partial);
  nnloss_reduce<<<1, 256, 0, stream>>>(partial, out);
}